// Round 11
// baseline (180.039 us; speedup 1.0000x reference)
//
#include <hip/hip_runtime.h>
#include <hip/hip_bf16.h>
#include <stdint.h>

#define N_TOK 8192
#define D_K   1024
#define BM    256
#define BN    256
#define BK    64
#define NT    (D_K / BK)            // 16 K-tiles, 8 iterations x 2
#define HALF_E (128 * BK)           // 8192 elems = 16 KB per half-tile

typedef __attribute__((ext_vector_type(8))) short bf16x8;
typedef __attribute__((ext_vector_type(4))) float f32x4;

__global__ void zero_out_kernel(float* out) { out[0] = 0.0f; }

__device__ __forceinline__ unsigned short f32_to_bf16_rne(float x) {
  uint32_t u = __builtin_bit_cast(uint32_t, x);
  uint32_t r = (u >> 16) & 1u;
  u += 0x7fffu + r;
  return (unsigned short)(u >> 16);
}

__global__ void __launch_bounds__(256)
convert_kernel(const float* __restrict__ a, const float* __restrict__ b,
               ushort* __restrict__ oa, ushort* __restrict__ ob) {
  const size_t total4 = (size_t)N_TOK * D_K / 4;
  size_t i = (size_t)blockIdx.x * blockDim.x + threadIdx.x;
  size_t stride = (size_t)gridDim.x * blockDim.x;
  for (; i < total4; i += stride) {
    float4 va = ((const float4*)a)[i];
    float4 vb = ((const float4*)b)[i];
    ushort4 ua, ub;
    ua.x = f32_to_bf16_rne(va.x); ua.y = f32_to_bf16_rne(va.y);
    ua.z = f32_to_bf16_rne(va.z); ua.w = f32_to_bf16_rne(va.w);
    ub.x = f32_to_bf16_rne(vb.x); ub.y = f32_to_bf16_rne(vb.y);
    ub.z = f32_to_bf16_rne(vb.z); ub.w = f32_to_bf16_rne(vb.w);
    ((ushort4*)oa)[i] = ua;
    ((ushort4*)ob)[i] = ub;
  }
}

// Fused 256x256 bf16 MFMA GEMM + sigmoid-contrastive loss.
// 16x16x32 8-phase schedule. Fragment reads/MFMAs are MACROS (not lambdas
// with array params): array-parameter pointer decay forced af/bf0/bf1 into
// scratch (rule #20) — that was the 18 MB WRITE_SIZE and the ~35% MfmaUtil
// ceiling of R5-R9.
__global__ void __launch_bounds__(512, 1)
sigc_kernel(const ushort* __restrict__ A, const ushort* __restrict__ B,
            const int* __restrict__ labA, const int* __restrict__ labB,
            const float* __restrict__ scale_p, const float* __restrict__ bias_p,
            float* __restrict__ out) {
  // index: [op(A=0,B=1)<<2 | parity<<1 | half]
  __shared__ ushort sTile[8][HALF_E];     // 128 KB
  __shared__ int sLabA[BM];
  __shared__ int sLabB[BN];
  __shared__ float sPart[8];

  const int tid  = threadIdx.x;
  const int lane = tid & 63;
  const int wid  = tid >> 6;      // 0..7
  const int wr   = wid >> 2;      // 0..1 (M half: rows wr*128..)
  const int wc   = wid & 3;       // 0..3 (N quarter: cols wc*64..)
  const int lr   = lane & 15;
  const int sHi  = lane >> 4;     // 0..3

  // 2-D XCD region mapping (bijective): xcd = bid&7 owns block-rows
  // (xcd>>1)*8..+7 and block-cols (xcd&1)*16..+15; col-major within.
  const int bid  = (int)blockIdx.x;
  const int xcd  = bid & 7;
  const int ii   = bid >> 3;                    // 0..127
  const int rr   = (xcd >> 1) * 8 + (ii & 7);   // block-row 0..31
  const int cc   = (xcd & 1) * 16 + (ii >> 3);  // block-col 0..31
  const int bRow = rr * BM;
  const int bCol = cc * BN;

  if (tid < 256) sLabA[tid] = labA[bRow + tid];
  else           sLabB[tid - 256] = labB[bCol + (tid - 256)];

  // T2 (rule #21): linear LDS dest, XOR-swizzled global source column.
  auto stage = [&](const ushort* __restrict__ G, int gBase, int op,
                   int tile, int half, int ld) {
    const int par = tile & 1;
    ushort* d = &sTile[(op << 2) | (par << 1) | half][ld * 4096 + wid * 512];
    const int e    = ld * 4096 + tid * 8;
    const int row  = e >> 6;                    // 0..127 within half
    const int slot = (e >> 3) & 7;
    const int col  = (slot ^ (row & 7)) << 3;
    const ushort* g = G + (size_t)(gBase + half * 128 + row) * D_K
                        + tile * BK + col;
    __builtin_amdgcn_global_load_lds(
        (const __attribute__((address_space(1))) void*)g,
        (__attribute__((address_space(3))) void*)d, 16, 0, 0);
  };

  bf16x8 af[4][2], bf0[2][2], bf1[2][2];
  f32x4 acc[8][4];
#pragma unroll
  for (int i = 0; i < 8; ++i)
#pragma unroll
    for (int j = 0; j < 4; ++j) acc[i][j] = (f32x4){0.f, 0.f, 0.f, 0.f};

// Swizzled LDS fragment load (16B).
#define LDF(p, r, s) (*(const bf16x8*)&(p)[(r) * BK + (((s) ^ ((r) & 7)) << 3)])

#define RDA(par, ms) do {                                                  \
    const ushort* _p = sTile[((par) << 1) | wr];                           \
    _Pragma("unroll") for (int _mf = 0; _mf < 4; ++_mf) {                  \
      const int _r = (ms) * 64 + _mf * 16 + lr;                            \
      af[_mf][0] = LDF(_p, _r, sHi);                                       \
      af[_mf][1] = LDF(_p, _r, 4 + sHi);                                   \
    } } while (0)

#define RDB(par, ns, dst) do {                                             \
    const ushort* _p = sTile[4 | ((par) << 1) | (wc >> 1)];                \
    _Pragma("unroll") for (int _nf = 0; _nf < 2; ++_nf) {                  \
      const int _r = (wc & 1) * 64 + (ns) * 32 + _nf * 16 + lr;            \
      dst[_nf][0] = LDF(_p, _r, sHi);                                      \
      dst[_nf][1] = LDF(_p, _r, 4 + sHi);                                  \
    } } while (0)

#define MMAQ(ms, ns, bsrc) do {                                            \
    __builtin_amdgcn_s_setprio(1);                                         \
    _Pragma("unroll") for (int _ks = 0; _ks < 2; ++_ks)                    \
    _Pragma("unroll") for (int _mf = 0; _mf < 4; ++_mf)                    \
    _Pragma("unroll") for (int _nf = 0; _nf < 2; ++_nf)                    \
      acc[(ms) * 4 + _mf][(ns) * 2 + _nf] =                                \
          __builtin_amdgcn_mfma_f32_16x16x32_bf16(                         \
              af[_mf][_ks], bsrc[_nf][_ks],                                \
              acc[(ms) * 4 + _mf][(ns) * 2 + _nf], 0, 0, 0);               \
    __builtin_amdgcn_s_setprio(0); } while (0)

#define SYNC_MID() do {                                                    \
    __builtin_amdgcn_sched_barrier(0);                                     \
    __builtin_amdgcn_s_barrier();                                          \
    asm volatile("s_waitcnt lgkmcnt(0)" ::: "memory");                     \
    __builtin_amdgcn_sched_barrier(0); } while (0)

#define SYNC_END() do {                                                    \
    __builtin_amdgcn_sched_barrier(0);                                     \
    __builtin_amdgcn_s_barrier(); } while (0)

  // Prologue: tile 0 fully (8 loads) + tile 1's [A.l0 x2, B x4] (6 loads).
  stage(A, bRow, 0, 0, 0, 0); stage(A, bRow, 0, 0, 0, 1);
  stage(A, bRow, 0, 0, 1, 0); stage(A, bRow, 0, 0, 1, 1);
  stage(B, bCol, 1, 0, 0, 0); stage(B, bCol, 1, 0, 0, 1);
  stage(B, bCol, 1, 0, 1, 0); stage(B, bCol, 1, 0, 1, 1);
  stage(A, bRow, 0, 1, 0, 0); stage(A, bRow, 0, 1, 1, 0);
  stage(B, bCol, 1, 1, 0, 0); stage(B, bCol, 1, 1, 0, 1);
  stage(B, bCol, 1, 1, 1, 0); stage(B, bCol, 1, 1, 1, 1);
  asm volatile("s_waitcnt vmcnt(6)" ::: "memory");   // tile 0 landed
  __syncthreads();

  for (int t2 = 0; t2 < NT / 2; ++t2) {
    const int e = 2 * t2, o = e + 1;
    const bool more = (t2 < NT / 2 - 1);

    // p0: quadrant (0,0) of tile e; stage A.l1(o).
    RDA(0, 0); RDB(0, 0, bf0);
    stage(A, bRow, 0, o, 0, 1); stage(A, bRow, 0, o, 1, 1);
    SYNC_MID(); MMAQ(0, 0, bf0); SYNC_END();

    // p1: (0,1); stage A.l0(e+2).
    RDB(0, 1, bf1);
    if (more) { stage(A, bRow, 0, e + 2, 0, 0); stage(A, bRow, 0, e + 2, 1, 0); }
    SYNC_MID(); MMAQ(0, 1, bf1); SYNC_END();

    // p2: (1,1); stage B0(e+2).
    RDA(0, 1);
    if (more) { stage(B, bCol, 1, e + 2, 0, 0); stage(B, bCol, 1, e + 2, 0, 1); }
    SYNC_MID(); MMAQ(1, 1, bf1); SYNC_END();

    // p3: (1,0); stage B1(e+2); counted vmcnt -> tile o fully landed.
    if (more) { stage(B, bCol, 1, e + 2, 1, 0); stage(B, bCol, 1, e + 2, 1, 1); }
    if (more) asm volatile("s_waitcnt vmcnt(6)" ::: "memory");
    else      asm volatile("s_waitcnt vmcnt(0)" ::: "memory");
    SYNC_MID(); MMAQ(1, 0, bf0); SYNC_END();

    // p4: quadrant (0,0) of tile o; stage A.l1(e+2).
    RDA(1, 0); RDB(1, 0, bf0);
    if (more) { stage(A, bRow, 0, e + 2, 0, 1); stage(A, bRow, 0, e + 2, 1, 1); }
    SYNC_MID(); MMAQ(0, 0, bf0); SYNC_END();

    // p5: (0,1); stage A.l0(o+2).
    RDB(1, 1, bf1);
    if (more) { stage(A, bRow, 0, o + 2, 0, 0); stage(A, bRow, 0, o + 2, 1, 0); }
    SYNC_MID(); MMAQ(0, 1, bf1); SYNC_END();

    // p6: (1,1); stage B0(o+2).
    RDA(1, 1);
    if (more) { stage(B, bCol, 1, o + 2, 0, 0); stage(B, bCol, 1, o + 2, 0, 1); }
    SYNC_MID(); MMAQ(1, 1, bf1); SYNC_END();

    // p7: (1,0); stage B1(o+2); counted vmcnt -> tile e+2 fully landed.
    if (more) { stage(B, bCol, 1, o + 2, 1, 0); stage(B, bCol, 1, o + 2, 1, 1); }
    if (more) asm volatile("s_waitcnt vmcnt(6)" ::: "memory");
    SYNC_MID(); MMAQ(1, 0, bf0); SYNC_END();
  }

  // Epilogue (exp2-form): softplus contribution per pair =
  // ln2*(max(u,0)+log2(1+2^-|u|)), u = -label*logit*log2e.
  const float L2E = 1.4426950408889634f;
  const float sl2e = scale_p[0] * L2E;
  const float bl2e = bias_p[0] * L2E;
  float loss = 0.0f;
  const int cBase = lane & 15;
  const int rBase = (lane >> 4) * 4;
#pragma unroll
  for (int ms = 0; ms < 2; ++ms)
#pragma unroll
    for (int mf = 0; mf < 4; ++mf)
#pragma unroll
      for (int ns = 0; ns < 2; ++ns)
#pragma unroll
        for (int nf = 0; nf < 2; ++nf) {
          const int colL = sLabB[wc * 64 + ns * 32 + nf * 16 + cBase];
#pragma unroll
          for (int r = 0; r < 4; ++r) {
            const int rowL = sLabA[wr * 128 + ms * 64 + mf * 16 + rBase + r];
            const float u0 =
                fmaf(sl2e, acc[ms * 4 + mf][ns * 2 + nf][r], bl2e);
            const float u = (rowL == colL) ? -u0 : u0;
            loss += fmaxf(u, 0.0f) + log2f(1.0f + exp2f(-fabsf(u)));
          }
        }

#pragma unroll
  for (int off = 32; off > 0; off >>= 1) loss += __shfl_down(loss, off, 64);
  if (lane == 0) sPart[wid] = loss;
  __syncthreads();
  if (tid == 0) {
    float s = 0.f;
#pragma unroll
    for (int w = 0; w < 8; ++w) s += sPart[w];
    atomicAdd(out, s * (0.6931471805599453f / (float)N_TOK));
  }
}

extern "C" void kernel_launch(void* const* d_in, const int* in_sizes, int n_in,
                              void* d_out, int out_size, void* d_ws, size_t ws_size,
                              hipStream_t stream) {
  const float* a  = (const float*)d_in[0];
  const float* b  = (const float*)d_in[1];
  const int*   la = (const int*)d_in[2];
  const int*   lb = (const int*)d_in[3];
  const float* sc = (const float*)d_in[4];
  const float* bi = (const float*)d_in[5];
  float* out = (float*)d_out;

  ushort* wa = (ushort*)d_ws;                       // bf16 A, 16 MB
  ushort* wb = wa + (size_t)N_TOK * D_K;            // bf16 B, 16 MB

  zero_out_kernel<<<1, 1, 0, stream>>>(out);
  convert_kernel<<<2048, 256, 0, stream>>>(a, b, wa, wb);
  const int grid = (N_TOK / BM) * (N_TOK / BN);     // 1024
  sigc_kernel<<<grid, 512, 0, stream>>>(wa, wb, la, lb, sc, bi, out);
}

// Round 12
// 121.260 us; speedup vs baseline: 1.4847x; 1.4847x over previous
//
#include <hip/hip_runtime.h>
#include <hip/hip_bf16.h>
#include <stdint.h>

#define N_TOK 8192
#define D_K   1024
#define NB    128            // block tile (BM=BN=128)
#define BKF   128            // K per tile (fp8, one MFMA K-step)
#define NT    (D_K / BKF)    // 8 K-tiles
#define TILE_B (NB * BKF)    // 16384 bytes per operand tile

typedef __attribute__((ext_vector_type(4))) int   i32x4;
typedef __attribute__((ext_vector_type(8))) int   i32x8;
typedef __attribute__((ext_vector_type(4))) float f32x4;

__global__ void zero_out_kernel(float* out) { out[0] = 0.0f; }

// fp32 -> OCP e4m3fn, RNE, with subnormal handling (inputs ~N(0,1)).
__device__ __forceinline__ unsigned int f32_to_e4m3(float x) {
  uint32_t u = __builtin_bit_cast(uint32_t, x);
  unsigned int s = (u >> 24) & 0x80u;
  float ax = __builtin_fabsf(x);
  if (ax < 0.015625f) {                    // < 2^-6: subnormal
    int q = (int)rintf(ax * 512.0f);       // 0..8 (8 -> 0x08 = 2^-6 exact)
    return s | (unsigned int)q;
  }
  uint32_t au = u & 0x7FFFFFFFu;
  uint32_t v = au + 0x7FFFFu + ((au >> 20) & 1u);   // RNE at 3 mantissa bits
  int em = (int)(v >> 20) - 960;           // rebias 127->7 (<<3)
  if (em > 0x7E) em = 0x7E;                // clamp to 448 (0x7F = NaN)
  return s | (unsigned int)em;
}

__global__ void __launch_bounds__(256)
convert_kernel(const float* __restrict__ a, const float* __restrict__ b,
               unsigned int* __restrict__ oa, unsigned int* __restrict__ ob) {
  const size_t total4 = (size_t)N_TOK * D_K / 4;
  size_t i = (size_t)blockIdx.x * blockDim.x + threadIdx.x;
  size_t stride = (size_t)gridDim.x * blockDim.x;
  for (; i < total4; i += stride) {
    float4 va = ((const float4*)a)[i];
    float4 vb = ((const float4*)b)[i];
    oa[i] = f32_to_e4m3(va.x) | (f32_to_e4m3(va.y) << 8) |
            (f32_to_e4m3(va.z) << 16) | (f32_to_e4m3(va.w) << 24);
    ob[i] = f32_to_e4m3(vb.x) | (f32_to_e4m3(vb.y) << 8) |
            (f32_to_e4m3(vb.z) << 16) | (f32_to_e4m3(vb.w) << 24);
  }
}

// Fused 128x128-tile MX-fp8 MFMA GEMM + sigmoid-contrastive loss.
// m148-anchor structure: 4 waves (2x2, 64x64 per wave), BK=128, dbuf LDS
// (64 KB -> 2 blocks/CU), simple 2-barrier loop with vmcnt(8) counted wait.
// mfma_scale_f32_16x16x128_f8f6f4 with all E8M0 scales = 127 (1.0) makes
// the scale-operand layout irrelevant. T2 XOR swizzle (slot^row&7 on 16B
// slots of the 128B row) applied on global source + LDS read (rule #21).
__global__ void __launch_bounds__(256)
sigc_kernel(const unsigned char* __restrict__ A8,
            const unsigned char* __restrict__ B8,
            const int* __restrict__ labA, const int* __restrict__ labB,
            const float* __restrict__ scale_p, const float* __restrict__ bias_p,
            float* __restrict__ out) {
  __shared__ unsigned char sA[2][TILE_B];   // 32 KB
  __shared__ unsigned char sB[2][TILE_B];   // 32 KB
  __shared__ int sLabA[NB];
  __shared__ int sLabB[NB];
  __shared__ float sPart[4];

  const int tid  = threadIdx.x;
  const int lane = tid & 63;
  const int wid  = tid >> 6;      // 0..3
  const int wr   = wid >> 1;      // 0..1
  const int wc   = wid & 1;       // 0..1
  const int lr   = lane & 15;
  const int kq   = lane >> 4;     // 0..3 (K-quarter: 32B at kq*32)

  // 2-D XCD region mapping on the 64x64 block grid: xcd owns 16 block-rows
  // x 32 block-cols, col-major within (16 consecutive blocks share B-panel;
  // concurrent set ~2.5 MB < 4 MB L2).
  const int bid = (int)blockIdx.x;
  const int xcd = bid & 7;
  const int ii  = bid >> 3;                    // 0..511
  const int rr  = (xcd >> 1) * 16 + (ii & 15); // 0..63
  const int cc  = (xcd & 1) * 32 + (ii >> 4);  // 0..63
  const int bRow = rr * NB;
  const int bCol = cc * NB;

  if (tid < 128)      sLabA[tid] = labA[bRow + tid];
  else                sLabB[tid - 128] = labB[bCol + (tid - 128)];

  // Stage one 128x128B operand tile: 4 gload_lds/thread, linear LDS dest,
  // XOR-swizzled global source column.
  auto stageOp = [&](const unsigned char* __restrict__ G, int gBase,
                     unsigned char* dst, int t) {
#pragma unroll
    for (int ld = 0; ld < 4; ++ld) {
      const int e    = ld * 4096 + tid * 16;   // byte index in tile
      const int row  = e >> 7;                 // 0..127
      const int slot = (e >> 4) & 7;
      const int col  = (slot ^ (row & 7)) << 4;
      const unsigned char* g =
          G + (size_t)(gBase + row) * D_K + t * BKF + col;
      __builtin_amdgcn_global_load_lds(
          (const __attribute__((address_space(1))) void*)g,
          (__attribute__((address_space(3))) void*)(dst + ld * 4096 + wid * 1024),
          16, 0, 0);
    }
  };

  f32x4 acc[4][4];
#pragma unroll
  for (int i = 0; i < 4; ++i)
#pragma unroll
    for (int j = 0; j < 4; ++j) acc[i][j] = (f32x4){0.f, 0.f, 0.f, 0.f};

  // Prologue: stage tiles 0,1 (16 loads); wait oldest 8 (tile 0).
  stageOp(A8, bRow, sA[0], 0); stageOp(B8, bCol, sB[0], 0);
  stageOp(A8, bRow, sA[1], 1); stageOp(B8, bCol, sB[1], 1);
  asm volatile("s_waitcnt vmcnt(8)" ::: "memory");
  __syncthreads();

  for (int t = 0; t < NT; ++t) {
    const unsigned char* pA = sA[t & 1];
    const unsigned char* pB = sB[t & 1];

    // Fragment reads: lane holds 32 K-consecutive fp8 at k = kq*32
    // (two swizzled b128 at slots 2*kq, 2*kq+1).
    i32x8 afr[4], bfr[4];
#pragma unroll
    for (int f = 0; f < 4; ++f) {
      {
        const int r = wr * 64 + f * 16 + lr;
        const int s0 = 2 * kq, s1 = 2 * kq + 1;
        i32x4 lo = *(const i32x4*)&pA[r * BKF + ((s0 ^ (r & 7)) << 4)];
        i32x4 hi = *(const i32x4*)&pA[r * BKF + ((s1 ^ (r & 7)) << 4)];
        afr[f] = __builtin_shufflevector(lo, hi, 0, 1, 2, 3, 4, 5, 6, 7);
      }
      {
        const int r = wc * 64 + f * 16 + lr;
        const int s0 = 2 * kq, s1 = 2 * kq + 1;
        i32x4 lo = *(const i32x4*)&pB[r * BKF + ((s0 ^ (r & 7)) << 4)];
        i32x4 hi = *(const i32x4*)&pB[r * BKF + ((s1 ^ (r & 7)) << 4)];
        bfr[f] = __builtin_shufflevector(lo, hi, 0, 1, 2, 3, 4, 5, 6, 7);
      }
    }

    // 16 MFMA (K=128 each), scales = 1.0 (E8M0 127 in every byte).
#pragma unroll
    for (int mf = 0; mf < 4; ++mf)
#pragma unroll
      for (int nf = 0; nf < 4; ++nf)
        acc[mf][nf] = __builtin_amdgcn_mfma_scale_f32_16x16x128_f8f6f4(
            afr[mf], bfr[nf], acc[mf][nf], 0, 0,
            0, 0x7F7F7F7F, 0, 0x7F7F7F7F);

    if (t < NT - 1) {
      __builtin_amdgcn_sched_barrier(0);
      __builtin_amdgcn_s_barrier();          // readers done with buf[t&1]
      if (t < NT - 2) {
        stageOp(A8, bRow, sA[t & 1], t + 2);
        stageOp(B8, bCol, sB[t & 1], t + 2);
        asm volatile("s_waitcnt vmcnt(8)" ::: "memory");  // tile t+1 landed
      } else {
        asm volatile("s_waitcnt vmcnt(0)" ::: "memory");
      }
      __builtin_amdgcn_sched_barrier(0);
      __builtin_amdgcn_s_barrier();          // tile t+1 visible to all
    }
  }

  // Epilogue (exp2-form): per-pair loss = ln2*(max(u,0)+log2(1+2^-|u|)),
  // u = -label*logit*log2e; C/D layout: col=lane&15, row=(lane>>4)*4+r.
  const float L2E = 1.4426950408889634f;
  const float sl2e = scale_p[0] * L2E;
  const float bl2e = bias_p[0] * L2E;
  float loss = 0.0f;
  const int cBase = lane & 15;
  const int rBase = (lane >> 4) * 4;
#pragma unroll
  for (int mf = 0; mf < 4; ++mf)
#pragma unroll
    for (int nf = 0; nf < 4; ++nf) {
      const int colL = sLabB[wc * 64 + nf * 16 + cBase];
#pragma unroll
      for (int r = 0; r < 4; ++r) {
        const int rowL = sLabA[wr * 64 + mf * 16 + rBase + r];
        const float u0 = fmaf(sl2e, acc[mf][nf][r], bl2e);
        const float u = (rowL == colL) ? -u0 : u0;
        loss += fmaxf(u, 0.0f) + log2f(1.0f + exp2f(-fabsf(u)));
      }
    }

#pragma unroll
  for (int off = 32; off > 0; off >>= 1) loss += __shfl_down(loss, off, 64);
  if (lane == 0) sPart[wid] = loss;
  __syncthreads();
  if (tid == 0) {
    const float s = (sPart[0] + sPart[1]) + (sPart[2] + sPart[3]);
    atomicAdd(out, s * (0.6931471805599453f / (float)N_TOK));
  }
}

extern "C" void kernel_launch(void* const* d_in, const int* in_sizes, int n_in,
                              void* d_out, int out_size, void* d_ws, size_t ws_size,
                              hipStream_t stream) {
  const float* a  = (const float*)d_in[0];
  const float* b  = (const float*)d_in[1];
  const int*   la = (const int*)d_in[2];
  const int*   lb = (const int*)d_in[3];
  const float* sc = (const float*)d_in[4];
  const float* bi = (const float*)d_in[5];
  float* out = (float*)d_out;

  unsigned char* wa = (unsigned char*)d_ws;          // fp8 A, 8 MB
  unsigned char* wb = wa + (size_t)N_TOK * D_K;      // fp8 B, 8 MB

  zero_out_kernel<<<1, 1, 0, stream>>>(out);
  convert_kernel<<<2048, 256, 0, stream>>>(a, b, (unsigned int*)wa,
                                           (unsigned int*)wb);
  const int grid = (N_TOK / NB) * (N_TOK / NB);      // 4096
  sigc_kernel<<<grid, 256, 0, stream>>>(wa, wb, la, lb, sc, bi, out);
}

// Round 13
// 120.826 us; speedup vs baseline: 1.4901x; 1.0036x over previous
//
#include <hip/hip_runtime.h>
#include <hip/hip_bf16.h>
#include <stdint.h>

#define N_TOK 8192
#define D_K   1024
#define NB    128            // block tile (BM=BN=128)
#define BKF   128            // K per tile (fp8, one MFMA K-step)
#define NT    (D_K / BKF)    // 8 K-tiles
#define TILE_B (NB * BKF)    // 16384 bytes per operand tile

typedef __attribute__((ext_vector_type(4))) int   i32x4;
typedef __attribute__((ext_vector_type(8))) int   i32x8;
typedef __attribute__((ext_vector_type(4))) float f32x4;

__global__ void zero_out_kernel(float* out) { out[0] = 0.0f; }

// fp32 -> OCP e4m3fn, RNE, with subnormal handling (inputs ~N(0,1)).
__device__ __forceinline__ unsigned int f32_to_e4m3(float x) {
  uint32_t u = __builtin_bit_cast(uint32_t, x);
  unsigned int s = (u >> 24) & 0x80u;
  float ax = __builtin_fabsf(x);
  if (ax < 0.015625f) {                    // < 2^-6: subnormal
    int q = (int)rintf(ax * 512.0f);       // 0..8 (8 -> 0x08 = 2^-6 exact)
    return s | (unsigned int)q;
  }
  uint32_t au = u & 0x7FFFFFFFu;
  uint32_t v = au + 0x7FFFFu + ((au >> 20) & 1u);   // RNE at 3 mantissa bits
  int em = (int)(v >> 20) - 960;           // rebias 127->7 (<<3)
  if (em > 0x7E) em = 0x7E;                // clamp to 448 (0x7F = NaN)
  return s | (unsigned int)em;
}

__global__ void __launch_bounds__(256)
convert_kernel(const float* __restrict__ a, const float* __restrict__ b,
               unsigned int* __restrict__ oa, unsigned int* __restrict__ ob) {
  const size_t total4 = (size_t)N_TOK * D_K / 4;
  size_t i = (size_t)blockIdx.x * blockDim.x + threadIdx.x;
  size_t stride = (size_t)gridDim.x * blockDim.x;
  for (; i < total4; i += stride) {
    float4 va = ((const float4*)a)[i];
    float4 vb = ((const float4*)b)[i];
    oa[i] = f32_to_e4m3(va.x) | (f32_to_e4m3(va.y) << 8) |
            (f32_to_e4m3(va.z) << 16) | (f32_to_e4m3(va.w) << 24);
    ob[i] = f32_to_e4m3(vb.x) | (f32_to_e4m3(vb.y) << 8) |
            (f32_to_e4m3(vb.z) << 16) | (f32_to_e4m3(vb.w) << 24);
  }
}

// Fused 128x128-tile MX-fp8 MFMA GEMM + sigmoid-contrastive loss.
// R12 fix vs R11: counted wait is vmcnt(16), not vmcnt(8). Per tile we
// issue 16 loads (tile t+2) then must retire exactly tile t+1's 16 while
// leaving all of t+2's in flight. vmcnt(8) was retiring half of the
// just-issued batch -> one L2 round-trip on every tile's critical path.
__global__ void __launch_bounds__(256)
sigc_kernel(const unsigned char* __restrict__ A8,
            const unsigned char* __restrict__ B8,
            const int* __restrict__ labA, const int* __restrict__ labB,
            const float* __restrict__ scale_p, const float* __restrict__ bias_p,
            float* __restrict__ out) {
  __shared__ unsigned char sA[2][TILE_B];   // 32 KB
  __shared__ unsigned char sB[2][TILE_B];   // 32 KB
  __shared__ int sLabA[NB];
  __shared__ int sLabB[NB];
  __shared__ float sPart[4];

  const int tid  = threadIdx.x;
  const int lane = tid & 63;
  const int wid  = tid >> 6;      // 0..3
  const int wr   = wid >> 1;      // 0..1
  const int wc   = wid & 1;       // 0..1
  const int lr   = lane & 15;
  const int kq   = lane >> 4;     // 0..3 (K-quarter: 32B at kq*32)

  // 2-D XCD region mapping on the 64x64 block grid.
  const int bid = (int)blockIdx.x;
  const int xcd = bid & 7;
  const int ii  = bid >> 3;                    // 0..511
  const int rr  = (xcd >> 1) * 16 + (ii & 15); // 0..63
  const int cc  = (xcd & 1) * 32 + (ii >> 4);  // 0..63
  const int bRow = rr * NB;
  const int bCol = cc * NB;

  if (tid < 128)      sLabA[tid] = labA[bRow + tid];
  else                sLabB[tid - 128] = labB[bCol + (tid - 128)];

  // Stage one 128x128B operand tile: 4 gload_lds/thread, linear LDS dest,
  // XOR-swizzled global source column (rule #21 / T2).
  auto stageOp = [&](const unsigned char* __restrict__ G, int gBase,
                     unsigned char* dst, int t) {
#pragma unroll
    for (int ld = 0; ld < 4; ++ld) {
      const int e    = ld * 4096 + tid * 16;   // byte index in tile
      const int row  = e >> 7;                 // 0..127
      const int slot = (e >> 4) & 7;
      const int col  = (slot ^ (row & 7)) << 4;
      const unsigned char* g =
          G + (size_t)(gBase + row) * D_K + t * BKF + col;
      __builtin_amdgcn_global_load_lds(
          (const __attribute__((address_space(1))) void*)g,
          (__attribute__((address_space(3))) void*)(dst + ld * 4096 + wid * 1024),
          16, 0, 0);
    }
  };

  f32x4 acc[4][4];
#pragma unroll
  for (int i = 0; i < 4; ++i)
#pragma unroll
    for (int j = 0; j < 4; ++j) acc[i][j] = (f32x4){0.f, 0.f, 0.f, 0.f};

  // Prologue: stage tiles 0,1 (32 loads); retire tile 0 (leave 16 in flight).
  stageOp(A8, bRow, sA[0], 0); stageOp(B8, bCol, sB[0], 0);
  stageOp(A8, bRow, sA[1], 1); stageOp(B8, bCol, sB[1], 1);
  asm volatile("s_waitcnt vmcnt(16)" ::: "memory");
  __syncthreads();

  for (int t = 0; t < NT; ++t) {
    const unsigned char* pA = sA[t & 1];
    const unsigned char* pB = sB[t & 1];

    // Fragment reads: lane holds 32 K-consecutive fp8 at k = kq*32
    // (two swizzled b128 at slots 2*kq, 2*kq+1).
    i32x8 afr[4], bfr[4];
#pragma unroll
    for (int f = 0; f < 4; ++f) {
      {
        const int r = wr * 64 + f * 16 + lr;
        const int s0 = 2 * kq, s1 = 2 * kq + 1;
        i32x4 lo = *(const i32x4*)&pA[r * BKF + ((s0 ^ (r & 7)) << 4)];
        i32x4 hi = *(const i32x4*)&pA[r * BKF + ((s1 ^ (r & 7)) << 4)];
        afr[f] = __builtin_shufflevector(lo, hi, 0, 1, 2, 3, 4, 5, 6, 7);
      }
      {
        const int r = wc * 64 + f * 16 + lr;
        const int s0 = 2 * kq, s1 = 2 * kq + 1;
        i32x4 lo = *(const i32x4*)&pB[r * BKF + ((s0 ^ (r & 7)) << 4)];
        i32x4 hi = *(const i32x4*)&pB[r * BKF + ((s1 ^ (r & 7)) << 4)];
        bfr[f] = __builtin_shufflevector(lo, hi, 0, 1, 2, 3, 4, 5, 6, 7);
      }
    }

    // 16 MFMA (K=128 each), scales = 1.0 (E8M0 127 in every byte).
#pragma unroll
    for (int mf = 0; mf < 4; ++mf)
#pragma unroll
      for (int nf = 0; nf < 4; ++nf)
        acc[mf][nf] = __builtin_amdgcn_mfma_scale_f32_16x16x128_f8f6f4(
            afr[mf], bfr[nf], acc[mf][nf], 0, 0,
            0, 0x7F7F7F7F, 0, 0x7F7F7F7F);

    if (t < NT - 1) {
      __builtin_amdgcn_sched_barrier(0);
      __builtin_amdgcn_s_barrier();          // readers done with buf[t&1]
      if (t < NT - 2) {
        stageOp(A8, bRow, sA[t & 1], t + 2);
        stageOp(B8, bCol, sB[t & 1], t + 2);
        // Retire exactly tile t+1's 16 loads; keep t+2's 16 in flight (T4).
        asm volatile("s_waitcnt vmcnt(16)" ::: "memory");
      } else {
        asm volatile("s_waitcnt vmcnt(0)" ::: "memory");
      }
      __builtin_amdgcn_sched_barrier(0);
      __builtin_amdgcn_s_barrier();          // tile t+1 visible to all
    }
  }

  // Epilogue (exp2-form): per-pair loss = ln2*(max(u,0)+log2(1+2^-|u|)),
  // u = -label*logit*log2e; C/D layout: col=lane&15, row=(lane>>4)*4+r.
  const float L2E = 1.4426950408889634f;
  const float sl2e = scale_p[0] * L2E;
  const float bl2e = bias_p[0] * L2E;
  float loss = 0.0f;
  const int cBase = lane & 15;
  const int rBase = (lane >> 4) * 4;
#pragma unroll
  for (int mf = 0; mf < 4; ++mf)
#pragma unroll
    for (int nf = 0; nf < 4; ++nf) {
      const int colL = sLabB[wc * 64 + nf * 16 + cBase];
#pragma unroll
      for (int r = 0; r < 4; ++r) {
        const int rowL = sLabA[wr * 64 + mf * 16 + rBase + r];
        const float u0 = fmaf(sl2e, acc[mf][nf][r], bl2e);
        const float u = (rowL == colL) ? -u0 : u0;
        loss += fmaxf(u, 0.0f) + log2f(1.0f + exp2f(-fabsf(u)));
      }
    }

#pragma unroll
  for (int off = 32; off > 0; off >>= 1) loss += __shfl_down(loss, off, 64);
  if (lane == 0) sPart[wid] = loss;
  __syncthreads();
  if (tid == 0) {
    const float s = (sPart[0] + sPart[1]) + (sPart[2] + sPart[3]);
    atomicAdd(out, s * (0.6931471805599453f / (float)N_TOK));
  }
}

extern "C" void kernel_launch(void* const* d_in, const int* in_sizes, int n_in,
                              void* d_out, int out_size, void* d_ws, size_t ws_size,
                              hipStream_t stream) {
  const float* a  = (const float*)d_in[0];
  const float* b  = (const float*)d_in[1];
  const int*   la = (const int*)d_in[2];
  const int*   lb = (const int*)d_in[3];
  const float* sc = (const float*)d_in[4];
  const float* bi = (const float*)d_in[5];
  float* out = (float*)d_out;

  unsigned char* wa = (unsigned char*)d_ws;          // fp8 A, 8 MB
  unsigned char* wb = wa + (size_t)N_TOK * D_K;      // fp8 B, 8 MB

  zero_out_kernel<<<1, 1, 0, stream>>>(out);
  convert_kernel<<<2048, 256, 0, stream>>>(a, b, (unsigned int*)wa,
                                           (unsigned int*)wb);
  const int grid = (N_TOK / NB) * (N_TOK / NB);      // 4096
  sigc_kernel<<<grid, 256, 0, stream>>>(wa, wb, la, lb, sc, bi, out);
}